// Round 4
// baseline (103.966 us; speedup 1.0000x reference)
//
#include <hip/hip_runtime.h>
#include <math.h>

// Problem constants
#define B_N   2048
#define D_IN_ 16
#define Q_N   512
#define H_N   128

// Variant A (R1 config): QCHUNK=32
#define QCHUNK 32
#define NQC    (Q_N / QCHUNK)          // 16
#define QPC    (QCHUNK / 4)            // 8
// Variant B (occupancy probe): QCHUNK=16
#define QCHUNK_B 16
#define NQC_B    (Q_N / QCHUNK_B)      // 32
#define QPC_B    (QCHUNK_B / 4)        // 4

#define NB     8                       // rows per thread
#define RPB    16                      // rows per block
#define NRB    (B_N / RPB)             // 128

static constexpr float kC = 2.88539008177792681472f;  // 2 * log2(e)

// ---------------------------------------------------------------------------
// R4: in-run A/B probe round. Acquisitions are the scarce resource (4
// timeouts), so one launch = two dispatches, each a COMPLETE computation:
//   A: R1 kernel (QCHUNK=32, 33KB LDS, lb(256,4), 4 blk/CU)  -> writes out
//   B: occupancy probe (QCHUNK=16, 16.5KB LDS, lb(256,8))    -> writes d_ws
// rocprof reports per-dispatch counters -> within-run A/B of the occupancy
// theory + VGPR/scratch evidence for the spill theory, in ONE acquisition.
// This round's total time is sacrificed (sum of both); next round ships the
// winner alone.
//   Math (both variants, verified round-3 derivation):
//   out[b] = sum_chunks [ Sc*(sumW2+b2) + sum_h W2[h] * sum_quads N(F)/P(F) ]
//   E = exp2(kC*u_qh), F = exp2(kC*v_bh); N deg3 (y folded), P deg4 (p0=1).
// ---------------------------------------------------------------------------
__global__ __launch_bounds__(256, 4) void fused_kernel_a(
    const float* __restrict__ input,
    const float* __restrict__ eq,
    const float* __restrict__ qx,
    const float* __restrict__ W1,
    const float* __restrict__ b1,
    const float* __restrict__ W2,
    const float* __restrict__ b2,
    float* __restrict__ out)
{
    __shared__ float c_s[QPC * 8 * H_N];     // 32 KB: [quad][coef][h]
    __shared__ float in_s[RPB * D_IN_];
    __shared__ float qx_s[QCHUNK * 2];
    __shared__ float y_s[QCHUNK];            // -2*sin(qx.eq)
    __shared__ float part[4][NB];
    __shared__ float Sc_s, w2sum_s;

    const int t    = threadIdx.x;
    const int rb   = blockIdx.x & (NRB - 1);
    const int qc   = blockIdx.x >> 7;
    const int h    = t & 127;
    const int bg   = t >> 7;
    const int lane = t & 63;
    const int w    = t >> 6;

    in_s[t] = input[rb * (RPB * D_IN_) + t];
    if (t < QCHUNK * 2) qx_s[t] = qx[qc * (QCHUNK * 2) + t];
    if (w == 0) {
        float s = 0.0f;
        if (lane < QCHUNK) {
            const int q = qc * QCHUNK + lane;
            const float a  = fmaf(qx[2 * q + 1], eq[1], qx[2 * q] * eq[0]);
            const float yv = sinf(a);
            y_s[lane] = -2.0f * yv;
            s = yv;
        }
        #pragma unroll
        for (int off = 32; off >= 1; off >>= 1)
            s += __shfl_down(s, off, 64);
        if (lane == 0) Sc_s = s;
    }
    if (w == 1) {
        float s = W2[lane] + W2[64 + lane];
        #pragma unroll
        for (int off = 32; off >= 1; off >>= 1)
            s += __shfl_down(s, off, 64);
        if (lane == 0) w2sum_s = s;
    }
    const float w2 = W2[h];
    __syncthreads();

    // phase 1: coef tile; thread (h,bg) builds quads bg*4+{0..3}
    {
        const float w1a = W1[h], w1b = W1[H_N + h], bh = b1[h];
        #pragma unroll
        for (int k = 0; k < 4; ++k) {
            const int qd = bg * 4 + k;
            float n0 = 0, n1 = 0, n2 = 0, n3 = 0;
            float p1 = 0, p2 = 0, p3 = 0, p4 = 0;
            #pragma unroll
            for (int i = 0; i < 4; ++i) {
                const int ql = qd * 4 + i;
                const float x0 = qx_s[2 * ql], x1 = qx_s[2 * ql + 1];
                const float u = fmaf(x1, w1b, fmaf(x0, w1a, bh));
                const float E = __builtin_amdgcn_exp2f(u * kC);
                const float y = y_s[ql];
                n3 = fmaf(E, n2, fmaf(y, p3, n3));
                n2 = fmaf(E, n1, fmaf(y, p2, n2));
                n1 = fmaf(E, n0, fmaf(y, p1, n1));
                n0 = n0 + y;
                p4 = fmaf(E, p3, p4);
                p3 = fmaf(E, p2, p3);
                p2 = fmaf(E, p1, p2);
                p1 = p1 + E;
            }
            float* dst = c_s + qd * (8 * H_N) + h;
            dst[0 * H_N] = n0; dst[1 * H_N] = n1;
            dst[2 * H_N] = n2; dst[3 * H_N] = n3;
            dst[4 * H_N] = p1; dst[5 * H_N] = p2;
            dst[6 * H_N] = p3; dst[7 * H_N] = p4;
        }
    }

    // phase 2: F for my 8 rows (streams W1, no big register array)
    float F[NB], acc[NB];
    {
        float s[NB];
        #pragma unroll
        for (int r = 0; r < NB; ++r) s[r] = 0.0f;
        const float4* in4 = (const float4*)in_s;
        #pragma unroll
        for (int k = 0; k < 4; ++k) {
            const float wa = W1[(2 + 4 * k + 0) * H_N + h];
            const float wb = W1[(2 + 4 * k + 1) * H_N + h];
            const float wc = W1[(2 + 4 * k + 2) * H_N + h];
            const float wd = W1[(2 + 4 * k + 3) * H_N + h];
            #pragma unroll
            for (int r = 0; r < NB; ++r) {
                const float4 a = in4[(bg * NB + r) * 4 + k];
                float sr = s[r];
                sr = fmaf(a.x, wa, sr);
                sr = fmaf(a.y, wb, sr);
                sr = fmaf(a.z, wc, sr);
                sr = fmaf(a.w, wd, sr);
                s[r] = sr;
            }
        }
        #pragma unroll
        for (int r = 0; r < NB; ++r) {
            F[r] = __builtin_amdgcn_exp2f(s[r] * kC);
            acc[r] = 0.0f;
        }
    }
    __syncthreads();

    // phase 3: rational inner loop
    #pragma unroll 2
    for (int qd = 0; qd < QPC; ++qd) {
        const float* cp = c_s + qd * (8 * H_N) + h;
        const float n0 = cp[0 * H_N], n1 = cp[1 * H_N];
        const float n2 = cp[2 * H_N], n3 = cp[3 * H_N];
        const float c1 = cp[4 * H_N], c2 = cp[5 * H_N];
        const float c3 = cp[6 * H_N], c4 = cp[7 * H_N];
        #pragma unroll
        for (int r = 0; r < NB; ++r) {
            const float Fr  = F[r];
            const float den = fmaf(fmaf(fmaf(fmaf(c4, Fr, c3), Fr, c2), Fr, c1), Fr, 1.0f);
            const float num = fmaf(fmaf(fmaf(n3, Fr, n2), Fr, n1), Fr, n0);
            acc[r] = fmaf(num, __builtin_amdgcn_rcpf(den), acc[r]);
        }
    }

    // epilogue
    #pragma unroll
    for (int r = 0; r < NB; ++r) {
        float p = acc[r] * w2;
        #pragma unroll
        for (int off = 32; off >= 1; off >>= 1)
            p += __shfl_down(p, off, 64);
        if (lane == 0) part[w][r] = p;
    }
    __syncthreads();

    if (t < 16) {
        const int r = t & 7, g = t >> 3;
        const float k0c = Sc_s * (w2sum_s + b2[0]);
        const float s = part[2 * g][r] + part[2 * g + 1][r] + k0c;
        atomicAdd(out + rb * RPB + g * NB + r, s);
    }
}

// ---------------------------------------------------------------------------
// Variant B: QCHUNK=16, 16.5 KB LDS, lb(256,8) -> target 8 blocks/CU.
// Complete computation; accumulates into ws (NOT out). Identical math.
// ---------------------------------------------------------------------------
__global__ __launch_bounds__(256, 8) void fused_kernel_probe(
    const float* __restrict__ input,
    const float* __restrict__ eq,
    const float* __restrict__ qx,
    const float* __restrict__ W1,
    const float* __restrict__ b1,
    const float* __restrict__ W2,
    const float* __restrict__ b2,
    float* __restrict__ wsout)
{
    __shared__ float c_s[QPC_B * 8 * H_N];   // 16 KB
    __shared__ float in_s[RPB * D_IN_];
    __shared__ float qx_s[QCHUNK_B * 2];
    __shared__ float y_s[QCHUNK_B];
    __shared__ float part[4][NB];
    __shared__ float Sc_s, w2sum_s;

    const int t    = threadIdx.x;
    const int rb   = blockIdx.x & (NRB - 1);
    const int qc   = blockIdx.x >> 7;        // [0,32)
    const int h    = t & 127;
    const int bg   = t >> 7;
    const int lane = t & 63;
    const int w    = t >> 6;

    in_s[t] = input[rb * (RPB * D_IN_) + t];
    if (t < QCHUNK_B * 2) qx_s[t] = qx[qc * (QCHUNK_B * 2) + t];
    if (w == 0) {
        float s = 0.0f;
        if (lane < QCHUNK_B) {
            const int q = qc * QCHUNK_B + lane;
            const float a  = fmaf(qx[2 * q + 1], eq[1], qx[2 * q] * eq[0]);
            const float yv = sinf(a);
            y_s[lane] = -2.0f * yv;
            s = yv;
        }
        #pragma unroll
        for (int off = 32; off >= 1; off >>= 1)
            s += __shfl_down(s, off, 64);
        if (lane == 0) Sc_s = s;
    }
    if (w == 1) {
        float s = W2[lane] + W2[64 + lane];
        #pragma unroll
        for (int off = 32; off >= 1; off >>= 1)
            s += __shfl_down(s, off, 64);
        if (lane == 0) w2sum_s = s;
    }
    const float w2 = W2[h];
    __syncthreads();

    // phase 1: thread (h,bg) builds quads bg*2+{0,1}
    {
        const float w1a = W1[h], w1b = W1[H_N + h], bh = b1[h];
        #pragma unroll
        for (int k = 0; k < 2; ++k) {
            const int qd = bg * 2 + k;       // [0,4)
            float n0 = 0, n1 = 0, n2 = 0, n3 = 0;
            float p1 = 0, p2 = 0, p3 = 0, p4 = 0;
            #pragma unroll
            for (int i = 0; i < 4; ++i) {
                const int ql = qd * 4 + i;   // [0,16)
                const float x0 = qx_s[2 * ql], x1 = qx_s[2 * ql + 1];
                const float u = fmaf(x1, w1b, fmaf(x0, w1a, bh));
                const float E = __builtin_amdgcn_exp2f(u * kC);
                const float y = y_s[ql];
                n3 = fmaf(E, n2, fmaf(y, p3, n3));
                n2 = fmaf(E, n1, fmaf(y, p2, n2));
                n1 = fmaf(E, n0, fmaf(y, p1, n1));
                n0 = n0 + y;
                p4 = fmaf(E, p3, p4);
                p3 = fmaf(E, p2, p3);
                p2 = fmaf(E, p1, p2);
                p1 = p1 + E;
            }
            float* dst = c_s + qd * (8 * H_N) + h;
            dst[0 * H_N] = n0; dst[1 * H_N] = n1;
            dst[2 * H_N] = n2; dst[3 * H_N] = n3;
            dst[4 * H_N] = p1; dst[5 * H_N] = p2;
            dst[6 * H_N] = p3; dst[7 * H_N] = p4;
        }
    }

    // phase 2: F for my 8 rows
    float F[NB], acc[NB];
    {
        float s[NB];
        #pragma unroll
        for (int r = 0; r < NB; ++r) s[r] = 0.0f;
        const float4* in4 = (const float4*)in_s;
        #pragma unroll
        for (int k = 0; k < 4; ++k) {
            const float wa = W1[(2 + 4 * k + 0) * H_N + h];
            const float wb = W1[(2 + 4 * k + 1) * H_N + h];
            const float wc = W1[(2 + 4 * k + 2) * H_N + h];
            const float wd = W1[(2 + 4 * k + 3) * H_N + h];
            #pragma unroll
            for (int r = 0; r < NB; ++r) {
                const float4 a = in4[(bg * NB + r) * 4 + k];
                float sr = s[r];
                sr = fmaf(a.x, wa, sr);
                sr = fmaf(a.y, wb, sr);
                sr = fmaf(a.z, wc, sr);
                sr = fmaf(a.w, wd, sr);
                s[r] = sr;
            }
        }
        #pragma unroll
        for (int r = 0; r < NB; ++r) {
            F[r] = __builtin_amdgcn_exp2f(s[r] * kC);
            acc[r] = 0.0f;
        }
    }
    __syncthreads();

    // phase 3
    #pragma unroll 2
    for (int qd = 0; qd < QPC_B; ++qd) {
        const float* cp = c_s + qd * (8 * H_N) + h;
        const float n0 = cp[0 * H_N], n1 = cp[1 * H_N];
        const float n2 = cp[2 * H_N], n3 = cp[3 * H_N];
        const float c1 = cp[4 * H_N], c2 = cp[5 * H_N];
        const float c3 = cp[6 * H_N], c4 = cp[7 * H_N];
        #pragma unroll
        for (int r = 0; r < NB; ++r) {
            const float Fr  = F[r];
            const float den = fmaf(fmaf(fmaf(fmaf(c4, Fr, c3), Fr, c2), Fr, c1), Fr, 1.0f);
            const float num = fmaf(fmaf(fmaf(n3, Fr, n2), Fr, n1), Fr, n0);
            acc[r] = fmaf(num, __builtin_amdgcn_rcpf(den), acc[r]);
        }
    }

    // epilogue -> workspace
    #pragma unroll
    for (int r = 0; r < NB; ++r) {
        float p = acc[r] * w2;
        #pragma unroll
        for (int off = 32; off >= 1; off >>= 1)
            p += __shfl_down(p, off, 64);
        if (lane == 0) part[w][r] = p;
    }
    __syncthreads();

    if (t < 16) {
        const int r = t & 7, g = t >> 3;
        const float k0c = Sc_s * (w2sum_s + b2[0]);
        const float s = part[2 * g][r] + part[2 * g + 1][r] + k0c;
        atomicAdd(wsout + rb * RPB + g * NB + r, s);
    }
}

// ---------------------------------------------------------------------------
extern "C" void kernel_launch(void* const* d_in, const int* in_sizes, int n_in,
                              void* d_out, int out_size, void* d_ws, size_t ws_size,
                              hipStream_t stream)
{
    (void)in_sizes; (void)n_in;
    const float* input = (const float*)d_in[0];
    const float* eq    = (const float*)d_in[1];
    const float* qx    = (const float*)d_in[2];
    const float* W1    = (const float*)d_in[3];
    const float* b1    = (const float*)d_in[4];
    const float* W2    = (const float*)d_in[5];
    const float* b2    = (const float*)d_in[6];
    float* out = (float*)d_out;

    hipMemsetAsync(d_out, 0, (size_t)out_size * sizeof(float), stream);
    // Dispatch A: verified result (R1 kernel, QCHUNK=32, lb(256,4))
    fused_kernel_a<<<dim3(NRB * NQC), dim3(256), 0, stream>>>(
        input, eq, qx, W1, b1, W2, b2, out);
    // Dispatch B: occupancy probe into workspace (QCHUNK=16, lb(256,8)).
    // Complete redundant computation; output discarded; guarded by ws_size.
    if (d_ws != nullptr && ws_size >= (size_t)B_N * sizeof(float)) {
        fused_kernel_probe<<<dim3(NRB * NQC_B), dim3(256), 0, stream>>>(
            input, eq, qx, W1, b1, W2, b2, (float*)d_ws);
    }
}

// Round 8
// 87.161 us; speedup vs baseline: 1.1928x; 1.1928x over previous
//
#include <hip/hip_runtime.h>
#include <math.h>

// Problem constants
#define B_N   2048
#define D_IN_ 16
#define Q_N   512
#define H_N   128

// Variant A: QCHUNK=32, lb(256,4); covers q-chunks [0,8)  -> q in [0,256)
#define QCHUNK 32
#define QPC    (QCHUNK / 4)            // 8
#define NQC_A  8                       // half of the 16 chunks
// Variant B: QCHUNK=16, lb(256,8); covers chunks [16,32)  -> q in [256,512)
#define QCHUNK_B 16
#define QPC_B    (QCHUNK_B / 4)        // 4
#define NQC_B    16                    // half of the 32 chunks

#define NB     8                       // rows per thread
#define RPB    16                      // rows per block
#define NRB    (B_N / RPB)             // 128

static constexpr float kC = 2.88539008177792681472f;  // 2 * log2(e)

// ---------------------------------------------------------------------------
// R5..R8: split-work A/B (resubmitted; acquisition timeouts x3 on this exact
// source). R4 taught: (a) touching d_ws triggers a 268MB poison fill
// (~39us/iter) that crowds kernel counters out of top-5; (b) both variants
// run <39us each. NO d_ws here. The q-sum is distributive -> dispatch A
// (QCHUNK=32, lb(256,4), 4 blk/CU) does q[0,256); dispatch B (QCHUNK=16,
// lb(256,8), 8 blk/CU) does q[256,512); both atomicAdd into out. Equal work
// shares -> per-dispatch dur_us is a direct occupancy-config A/B; headline
// = average of the two configs (~25-35us predicted) - bounded downside.
//   Math (verified in-harness R4, absmax 0.0):
//   out[b] = sum_chunks [ Sc*(sumW2+b2) + sum_h W2[h] * sum_quads N(F)/P(F) ]
//   E = exp2(kC*u_qh), F = exp2(kC*v_bh); N deg3 (y folded), P deg4 (p0=1).
// ---------------------------------------------------------------------------
__global__ __launch_bounds__(256, 4) void fused_kernel_a(
    const float* __restrict__ input,
    const float* __restrict__ eq,
    const float* __restrict__ qx,
    const float* __restrict__ W1,
    const float* __restrict__ b1,
    const float* __restrict__ W2,
    const float* __restrict__ b2,
    float* __restrict__ out)
{
    __shared__ float c_s[QPC * 8 * H_N];     // 32 KB: [quad][coef][h]
    __shared__ float in_s[RPB * D_IN_];
    __shared__ float qx_s[QCHUNK * 2];
    __shared__ float y_s[QCHUNK];            // -2*sin(qx.eq)
    __shared__ float part[4][NB];
    __shared__ float Sc_s, w2sum_s;

    const int t    = threadIdx.x;
    const int rb   = blockIdx.x & (NRB - 1);
    const int qc   = blockIdx.x >> 7;        // [0,8): chunks 0..7
    const int h    = t & 127;
    const int bg   = t >> 7;
    const int lane = t & 63;
    const int w    = t >> 6;

    in_s[t] = input[rb * (RPB * D_IN_) + t];
    if (t < QCHUNK * 2) qx_s[t] = qx[qc * (QCHUNK * 2) + t];
    if (w == 0) {
        float s = 0.0f;
        if (lane < QCHUNK) {
            const int q = qc * QCHUNK + lane;
            const float a  = fmaf(qx[2 * q + 1], eq[1], qx[2 * q] * eq[0]);
            const float yv = sinf(a);
            y_s[lane] = -2.0f * yv;
            s = yv;
        }
        #pragma unroll
        for (int off = 32; off >= 1; off >>= 1)
            s += __shfl_down(s, off, 64);
        if (lane == 0) Sc_s = s;
    }
    if (w == 1) {
        float s = W2[lane] + W2[64 + lane];
        #pragma unroll
        for (int off = 32; off >= 1; off >>= 1)
            s += __shfl_down(s, off, 64);
        if (lane == 0) w2sum_s = s;
    }
    const float w2 = W2[h];
    __syncthreads();

    // phase 1: coef tile; thread (h,bg) builds quads bg*4+{0..3}
    {
        const float w1a = W1[h], w1b = W1[H_N + h], bh = b1[h];
        #pragma unroll
        for (int k = 0; k < 4; ++k) {
            const int qd = bg * 4 + k;
            float n0 = 0, n1 = 0, n2 = 0, n3 = 0;
            float p1 = 0, p2 = 0, p3 = 0, p4 = 0;
            #pragma unroll
            for (int i = 0; i < 4; ++i) {
                const int ql = qd * 4 + i;
                const float x0 = qx_s[2 * ql], x1 = qx_s[2 * ql + 1];
                const float u = fmaf(x1, w1b, fmaf(x0, w1a, bh));
                const float E = __builtin_amdgcn_exp2f(u * kC);
                const float y = y_s[ql];
                n3 = fmaf(E, n2, fmaf(y, p3, n3));
                n2 = fmaf(E, n1, fmaf(y, p2, n2));
                n1 = fmaf(E, n0, fmaf(y, p1, n1));
                n0 = n0 + y;
                p4 = fmaf(E, p3, p4);
                p3 = fmaf(E, p2, p3);
                p2 = fmaf(E, p1, p2);
                p1 = p1 + E;
            }
            float* dst = c_s + qd * (8 * H_N) + h;
            dst[0 * H_N] = n0; dst[1 * H_N] = n1;
            dst[2 * H_N] = n2; dst[3 * H_N] = n3;
            dst[4 * H_N] = p1; dst[5 * H_N] = p2;
            dst[6 * H_N] = p3; dst[7 * H_N] = p4;
        }
    }

    // phase 2: F for my 8 rows (streams W1)
    float F[NB], acc[NB];
    {
        float s[NB];
        #pragma unroll
        for (int r = 0; r < NB; ++r) s[r] = 0.0f;
        const float4* in4 = (const float4*)in_s;
        #pragma unroll
        for (int k = 0; k < 4; ++k) {
            const float wa = W1[(2 + 4 * k + 0) * H_N + h];
            const float wb = W1[(2 + 4 * k + 1) * H_N + h];
            const float wc = W1[(2 + 4 * k + 2) * H_N + h];
            const float wd = W1[(2 + 4 * k + 3) * H_N + h];
            #pragma unroll
            for (int r = 0; r < NB; ++r) {
                const float4 a = in4[(bg * NB + r) * 4 + k];
                float sr = s[r];
                sr = fmaf(a.x, wa, sr);
                sr = fmaf(a.y, wb, sr);
                sr = fmaf(a.z, wc, sr);
                sr = fmaf(a.w, wd, sr);
                s[r] = sr;
            }
        }
        #pragma unroll
        for (int r = 0; r < NB; ++r) {
            F[r] = __builtin_amdgcn_exp2f(s[r] * kC);
            acc[r] = 0.0f;
        }
    }
    __syncthreads();

    // phase 3: rational inner loop
    #pragma unroll 2
    for (int qd = 0; qd < QPC; ++qd) {
        const float* cp = c_s + qd * (8 * H_N) + h;
        const float n0 = cp[0 * H_N], n1 = cp[1 * H_N];
        const float n2 = cp[2 * H_N], n3 = cp[3 * H_N];
        const float c1 = cp[4 * H_N], c2 = cp[5 * H_N];
        const float c3 = cp[6 * H_N], c4 = cp[7 * H_N];
        #pragma unroll
        for (int r = 0; r < NB; ++r) {
            const float Fr  = F[r];
            const float den = fmaf(fmaf(fmaf(fmaf(c4, Fr, c3), Fr, c2), Fr, c1), Fr, 1.0f);
            const float num = fmaf(fmaf(fmaf(n3, Fr, n2), Fr, n1), Fr, n0);
            acc[r] = fmaf(num, __builtin_amdgcn_rcpf(den), acc[r]);
        }
    }

    // epilogue
    #pragma unroll
    for (int r = 0; r < NB; ++r) {
        float p = acc[r] * w2;
        #pragma unroll
        for (int off = 32; off >= 1; off >>= 1)
            p += __shfl_down(p, off, 64);
        if (lane == 0) part[w][r] = p;
    }
    __syncthreads();

    if (t < 16) {
        const int r = t & 7, g = t >> 3;
        const float k0c = Sc_s * (w2sum_s + b2[0]);
        const float s = part[2 * g][r] + part[2 * g + 1][r] + k0c;
        atomicAdd(out + rb * RPB + g * NB + r, s);
    }
}

// ---------------------------------------------------------------------------
// Variant B: QCHUNK=16, ~17 KB LDS, lb(256,8) -> 8 blocks/CU target.
// Covers chunks [16,32) (q in [256,512)). atomicAdds into out.
// ---------------------------------------------------------------------------
__global__ __launch_bounds__(256, 8) void fused_kernel_b(
    const float* __restrict__ input,
    const float* __restrict__ eq,
    const float* __restrict__ qx,
    const float* __restrict__ W1,
    const float* __restrict__ b1,
    const float* __restrict__ W2,
    const float* __restrict__ b2,
    float* __restrict__ out)
{
    __shared__ float c_s[QPC_B * 8 * H_N];   // 16 KB
    __shared__ float in_s[RPB * D_IN_];
    __shared__ float qx_s[QCHUNK_B * 2];
    __shared__ float y_s[QCHUNK_B];
    __shared__ float part[4][NB];
    __shared__ float Sc_s, w2sum_s;

    const int t    = threadIdx.x;
    const int rb   = blockIdx.x & (NRB - 1);
    const int qc   = 16 + (blockIdx.x >> 7); // [16,32): chunks 16..31
    const int h    = t & 127;
    const int bg   = t >> 7;
    const int lane = t & 63;
    const int w    = t >> 6;

    in_s[t] = input[rb * (RPB * D_IN_) + t];
    if (t < QCHUNK_B * 2) qx_s[t] = qx[qc * (QCHUNK_B * 2) + t];
    if (w == 0) {
        float s = 0.0f;
        if (lane < QCHUNK_B) {
            const int q = qc * QCHUNK_B + lane;
            const float a  = fmaf(qx[2 * q + 1], eq[1], qx[2 * q] * eq[0]);
            const float yv = sinf(a);
            y_s[lane] = -2.0f * yv;
            s = yv;
        }
        #pragma unroll
        for (int off = 32; off >= 1; off >>= 1)
            s += __shfl_down(s, off, 64);
        if (lane == 0) Sc_s = s;
    }
    if (w == 1) {
        float s = W2[lane] + W2[64 + lane];
        #pragma unroll
        for (int off = 32; off >= 1; off >>= 1)
            s += __shfl_down(s, off, 64);
        if (lane == 0) w2sum_s = s;
    }
    const float w2 = W2[h];
    __syncthreads();

    // phase 1: thread (h,bg) builds quads bg*2+{0,1}
    {
        const float w1a = W1[h], w1b = W1[H_N + h], bh = b1[h];
        #pragma unroll
        for (int k = 0; k < 2; ++k) {
            const int qd = bg * 2 + k;       // [0,4)
            float n0 = 0, n1 = 0, n2 = 0, n3 = 0;
            float p1 = 0, p2 = 0, p3 = 0, p4 = 0;
            #pragma unroll
            for (int i = 0; i < 4; ++i) {
                const int ql = qd * 4 + i;   // [0,16)
                const float x0 = qx_s[2 * ql], x1 = qx_s[2 * ql + 1];
                const float u = fmaf(x1, w1b, fmaf(x0, w1a, bh));
                const float E = __builtin_amdgcn_exp2f(u * kC);
                const float y = y_s[ql];
                n3 = fmaf(E, n2, fmaf(y, p3, n3));
                n2 = fmaf(E, n1, fmaf(y, p2, n2));
                n1 = fmaf(E, n0, fmaf(y, p1, n1));
                n0 = n0 + y;
                p4 = fmaf(E, p3, p4);
                p3 = fmaf(E, p2, p3);
                p2 = fmaf(E, p1, p2);
                p1 = p1 + E;
            }
            float* dst = c_s + qd * (8 * H_N) + h;
            dst[0 * H_N] = n0; dst[1 * H_N] = n1;
            dst[2 * H_N] = n2; dst[3 * H_N] = n3;
            dst[4 * H_N] = p1; dst[5 * H_N] = p2;
            dst[6 * H_N] = p3; dst[7 * H_N] = p4;
        }
    }

    // phase 2: F for my 8 rows
    float F[NB], acc[NB];
    {
        float s[NB];
        #pragma unroll
        for (int r = 0; r < NB; ++r) s[r] = 0.0f;
        const float4* in4 = (const float4*)in_s;
        #pragma unroll
        for (int k = 0; k < 4; ++k) {
            const float wa = W1[(2 + 4 * k + 0) * H_N + h];
            const float wb = W1[(2 + 4 * k + 1) * H_N + h];
            const float wc = W1[(2 + 4 * k + 2) * H_N + h];
            const float wd = W1[(2 + 4 * k + 3) * H_N + h];
            #pragma unroll
            for (int r = 0; r < NB; ++r) {
                const float4 a = in4[(bg * NB + r) * 4 + k];
                float sr = s[r];
                sr = fmaf(a.x, wa, sr);
                sr = fmaf(a.y, wb, sr);
                sr = fmaf(a.z, wc, sr);
                sr = fmaf(a.w, wd, sr);
                s[r] = sr;
            }
        }
        #pragma unroll
        for (int r = 0; r < NB; ++r) {
            F[r] = __builtin_amdgcn_exp2f(s[r] * kC);
            acc[r] = 0.0f;
        }
    }
    __syncthreads();

    // phase 3
    #pragma unroll 2
    for (int qd = 0; qd < QPC_B; ++qd) {
        const float* cp = c_s + qd * (8 * H_N) + h;
        const float n0 = cp[0 * H_N], n1 = cp[1 * H_N];
        const float n2 = cp[2 * H_N], n3 = cp[3 * H_N];
        const float c1 = cp[4 * H_N], c2 = cp[5 * H_N];
        const float c3 = cp[6 * H_N], c4 = cp[7 * H_N];
        #pragma unroll
        for (int r = 0; r < NB; ++r) {
            const float Fr  = F[r];
            const float den = fmaf(fmaf(fmaf(fmaf(c4, Fr, c3), Fr, c2), Fr, c1), Fr, 1.0f);
            const float num = fmaf(fmaf(fmaf(n3, Fr, n2), Fr, n1), Fr, n0);
            acc[r] = fmaf(num, __builtin_amdgcn_rcpf(den), acc[r]);
        }
    }

    // epilogue
    #pragma unroll
    for (int r = 0; r < NB; ++r) {
        float p = acc[r] * w2;
        #pragma unroll
        for (int off = 32; off >= 1; off >>= 1)
            p += __shfl_down(p, off, 64);
        if (lane == 0) part[w][r] = p;
    }
    __syncthreads();

    if (t < 16) {
        const int r = t & 7, g = t >> 3;
        const float k0c = Sc_s * (w2sum_s + b2[0]);
        const float s = part[2 * g][r] + part[2 * g + 1][r] + k0c;
        atomicAdd(out + rb * RPB + g * NB + r, s);
    }
}

// ---------------------------------------------------------------------------
extern "C" void kernel_launch(void* const* d_in, const int* in_sizes, int n_in,
                              void* d_out, int out_size, void* d_ws, size_t ws_size,
                              hipStream_t stream)
{
    (void)in_sizes; (void)n_in; (void)d_ws; (void)ws_size;  // d_ws untouched!
    const float* input = (const float*)d_in[0];
    const float* eq    = (const float*)d_in[1];
    const float* qx    = (const float*)d_in[2];
    const float* W1    = (const float*)d_in[3];
    const float* b1    = (const float*)d_in[4];
    const float* W2    = (const float*)d_in[5];
    const float* b2    = (const float*)d_in[6];
    float* out = (float*)d_out;

    hipMemsetAsync(d_out, 0, (size_t)out_size * sizeof(float), stream);
    // A: q in [0,256), QCHUNK=32, 4 blk/CU, grid 1024 = exactly fills chip
    fused_kernel_a<<<dim3(NRB * NQC_A), dim3(256), 0, stream>>>(
        input, eq, qx, W1, b1, W2, b2, out);
    // B: q in [256,512), QCHUNK=16, 8 blk/CU, grid 2048 = exactly fills chip
    fused_kernel_b<<<dim3(NRB * NQC_B), dim3(256), 0, stream>>>(
        input, eq, qx, W1, b1, W2, b2, out);
}

// Round 10
// 83.332 us; speedup vs baseline: 1.2476x; 1.0460x over previous
//
#include <hip/hip_runtime.h>
#include <math.h>

// Problem constants
#define B_N   2048
#define D_IN_ 16
#define Q_N   512
#define H_N   128

#define QCHUNK 32                      // q's per block
#define NQC    (Q_N / QCHUNK)          // 16
#define QPC    (QCHUNK / 4)            // 8
#define NB     8                       // rows per thread
#define RPB    16                      // rows per block
#define NRB    (B_N / RPB)             // 128

static constexpr float kC = 2.88539008177792681472f;  // 2 * log2(e)

// ---------------------------------------------------------------------------
// R9/R10: SINGLE dispatch, full work (= R4's verified dispatch A alone).
// Resubmitted unchanged (R9 hit acquisition timeout). Harness model from
// R4+R8 data:
//   headline = fill(~40us, unconditional d_ws re-poison) + overhead + kernels
//   R4: 104 = 40 + C + A_full + B_full ; R8: 87 = 40 + C + (A+B)/2
//   => A_full+B_full ~= 34us (17 each; occupancy A/B TIED -> occupancy
//   theory dead), C ~= 29us => ~10-14.5us per dispatch launch/sync overhead.
// So: cut dispatches. Prediction: headline ~72-76 if overhead per-dispatch,
// ~60-65 if mostly fixed — the value discriminates. Either way < 82.7
// baseline and < 87 (R8). Rejected alternatives (desk-check): grid-128
// no-atomic variant (half CUs idle, net +), coef-precompute into d_ws
// (+1 dispatch > redundancy saved under current model).
//   Math (verified in-harness R4, absmax 0.0 on this exact kernel):
//   out[b] = sum_chunks [ Sc*(sumW2+b2) + sum_h W2[h] * sum_quads N(F)/P(F) ]
//   E = exp2(kC*u_qh), F = exp2(kC*v_bh); N deg3 (y folded), P deg4 (p0=1).
// ---------------------------------------------------------------------------
__global__ __launch_bounds__(256, 4) void fused_kernel(
    const float* __restrict__ input,
    const float* __restrict__ eq,
    const float* __restrict__ qx,
    const float* __restrict__ W1,
    const float* __restrict__ b1,
    const float* __restrict__ W2,
    const float* __restrict__ b2,
    float* __restrict__ out)
{
    __shared__ float c_s[QPC * 8 * H_N];     // 32 KB: [quad][coef][h]
    __shared__ float in_s[RPB * D_IN_];
    __shared__ float qx_s[QCHUNK * 2];
    __shared__ float y_s[QCHUNK];            // -2*sin(qx.eq)
    __shared__ float part[4][NB];
    __shared__ float Sc_s, w2sum_s;

    const int t    = threadIdx.x;
    const int rb   = blockIdx.x & (NRB - 1); // row-block [0,128)
    const int qc   = blockIdx.x >> 7;        // q-chunk   [0,16)
    const int h    = t & 127;
    const int bg   = t >> 7;
    const int lane = t & 63;
    const int w    = t >> 6;

    // ---- phase 0: stage input rows + qx chunk; y + Sc (wave 0); sum W2 ----
    in_s[t] = input[rb * (RPB * D_IN_) + t];
    if (t < QCHUNK * 2) qx_s[t] = qx[qc * (QCHUNK * 2) + t];
    if (w == 0) {
        float s = 0.0f;
        if (lane < QCHUNK) {
            const int q = qc * QCHUNK + lane;
            const float a  = fmaf(qx[2 * q + 1], eq[1], qx[2 * q] * eq[0]);
            const float yv = sinf(a);
            y_s[lane] = -2.0f * yv;
            s = yv;
        }
        #pragma unroll
        for (int off = 32; off >= 1; off >>= 1)
            s += __shfl_down(s, off, 64);
        if (lane == 0) Sc_s = s;
    }
    if (w == 1) {
        float s = W2[lane] + W2[64 + lane];
        #pragma unroll
        for (int off = 32; off >= 1; off >>= 1)
            s += __shfl_down(s, off, 64);
        if (lane == 0) w2sum_s = s;
    }
    const float w2 = W2[h];
    __syncthreads();

    // ---- phase 1: coef tile; thread (h,bg) builds quads bg*4+{0..3} ----
    {
        const float w1a = W1[h], w1b = W1[H_N + h], bh = b1[h];
        #pragma unroll
        for (int k = 0; k < 4; ++k) {
            const int qd = bg * 4 + k;
            float n0 = 0, n1 = 0, n2 = 0, n3 = 0;
            float p1 = 0, p2 = 0, p3 = 0, p4 = 0;
            #pragma unroll
            for (int i = 0; i < 4; ++i) {
                const int ql = qd * 4 + i;
                const float x0 = qx_s[2 * ql], x1 = qx_s[2 * ql + 1];
                const float u = fmaf(x1, w1b, fmaf(x0, w1a, bh));
                const float E = __builtin_amdgcn_exp2f(u * kC);
                const float y = y_s[ql];
                n3 = fmaf(E, n2, fmaf(y, p3, n3));
                n2 = fmaf(E, n1, fmaf(y, p2, n2));
                n1 = fmaf(E, n0, fmaf(y, p1, n1));
                n0 = n0 + y;
                p4 = fmaf(E, p3, p4);
                p3 = fmaf(E, p2, p3);
                p2 = fmaf(E, p1, p2);
                p1 = p1 + E;
            }
            float* dst = c_s + qd * (8 * H_N) + h;
            dst[0 * H_N] = n0; dst[1 * H_N] = n1;
            dst[2 * H_N] = n2; dst[3 * H_N] = n3;
            dst[4 * H_N] = p1; dst[5 * H_N] = p2;
            dst[6 * H_N] = p3; dst[7 * H_N] = p4;
        }
    }

    // ---- phase 2: F for my 8 rows (streams W1) ----
    float F[NB], acc[NB];
    {
        float s[NB];
        #pragma unroll
        for (int r = 0; r < NB; ++r) s[r] = 0.0f;
        const float4* in4 = (const float4*)in_s;
        #pragma unroll
        for (int k = 0; k < 4; ++k) {
            const float wa = W1[(2 + 4 * k + 0) * H_N + h];
            const float wb = W1[(2 + 4 * k + 1) * H_N + h];
            const float wc = W1[(2 + 4 * k + 2) * H_N + h];
            const float wd = W1[(2 + 4 * k + 3) * H_N + h];
            #pragma unroll
            for (int r = 0; r < NB; ++r) {
                const float4 a = in4[(bg * NB + r) * 4 + k];
                float sr = s[r];
                sr = fmaf(a.x, wa, sr);
                sr = fmaf(a.y, wb, sr);
                sr = fmaf(a.z, wc, sr);
                sr = fmaf(a.w, wd, sr);
                s[r] = sr;
            }
        }
        #pragma unroll
        for (int r = 0; r < NB; ++r) {
            F[r] = __builtin_amdgcn_exp2f(s[r] * kC);
            acc[r] = 0.0f;
        }
    }
    __syncthreads();

    // ---- phase 3: rational inner loop (8 fma + 1 rcp per 4 elements) ----
    #pragma unroll 2
    for (int qd = 0; qd < QPC; ++qd) {
        const float* cp = c_s + qd * (8 * H_N) + h;
        const float n0 = cp[0 * H_N], n1 = cp[1 * H_N];
        const float n2 = cp[2 * H_N], n3 = cp[3 * H_N];
        const float c1 = cp[4 * H_N], c2 = cp[5 * H_N];
        const float c3 = cp[6 * H_N], c4 = cp[7 * H_N];
        #pragma unroll
        for (int r = 0; r < NB; ++r) {
            const float Fr  = F[r];
            const float den = fmaf(fmaf(fmaf(fmaf(c4, Fr, c3), Fr, c2), Fr, c1), Fr, 1.0f);
            const float num = fmaf(fmaf(fmaf(n3, Fr, n2), Fr, n1), Fr, n0);
            acc[r] = fmaf(num, __builtin_amdgcn_rcpf(den), acc[r]);
        }
    }

    // ---- epilogue: x W2[h], reduce over h, add per-chunk constant ----
    #pragma unroll
    for (int r = 0; r < NB; ++r) {
        float p = acc[r] * w2;
        #pragma unroll
        for (int off = 32; off >= 1; off >>= 1)
            p += __shfl_down(p, off, 64);
        if (lane == 0) part[w][r] = p;
    }
    __syncthreads();

    if (t < 16) {
        const int r = t & 7, g = t >> 3;
        const float k0c = Sc_s * (w2sum_s + b2[0]);
        const float s = part[2 * g][r] + part[2 * g + 1][r] + k0c;
        atomicAdd(out + rb * RPB + g * NB + r, s);
    }
}

// ---------------------------------------------------------------------------
extern "C" void kernel_launch(void* const* d_in, const int* in_sizes, int n_in,
                              void* d_out, int out_size, void* d_ws, size_t ws_size,
                              hipStream_t stream)
{
    (void)in_sizes; (void)n_in; (void)d_ws; (void)ws_size;
    const float* input = (const float*)d_in[0];
    const float* eq    = (const float*)d_in[1];
    const float* qx    = (const float*)d_in[2];
    const float* W1    = (const float*)d_in[3];
    const float* b1    = (const float*)d_in[4];
    const float* W2    = (const float*)d_in[5];
    const float* b2    = (const float*)d_in[6];
    float* out = (float*)d_out;

    hipMemsetAsync(d_out, 0, (size_t)out_size * sizeof(float), stream);
    // Single dispatch: grid 2048 = 128 row-blocks x 16 q-chunks, 4 blk/CU.
    fused_kernel<<<dim3(NRB * NQC), dim3(256), 0, stream>>>(
        input, eq, qx, W1, b1, W2, b2, out);
}

// Round 12
// 82.887 us; speedup vs baseline: 1.2543x; 1.0054x over previous
//
#include <hip/hip_runtime.h>
#include <math.h>

// Problem constants
#define B_N   2048
#define D_IN_ 16
#define Q_N   512
#define H_N   128

#define QCHUNK 32                      // q's per block
#define NQC    (Q_N / QCHUNK)          // 16
#define QPC    (QCHUNK / 4)            // 8
#define NB     8                       // rows per thread
#define RPB    16                      // rows per block
#define NRB    (B_N / RPB)             // 128

static constexpr float kC = 2.88539008177792681472f;  // 2 * log2(e)

// ---------------------------------------------------------------------------
// R11/R12: b128 LDS coefficient tile (single variable vs R10). Resubmitted
// unchanged (R11 hit acquisition timeout); swizzle re-desk-checked: f is an
// involution on bits 0-2, writer==reader expression -> pure relabel, correct.
// Harness model (R4+R8+R10 solved): headline = fill(39.7) + reset(~25) +
// memset + kernel(~15-17) => floor ~66-68us untouchable; kernel is the only
// elastic term. A/B tie (R8) at 4 vs 8 blk/CU => issue-bound, not latency.
// Excess vs ~8-9us issue model: 64 ds_read_b32 + 32 strided ds_write_b32
// per thread. This round: c_s repacked as [quad][256 float4-chunks] with
// XOR swizzle cw' = cw ^ ((cw>>3)&7)  (8 lanes/bank-quad = b128 structural
// minimum => conflict-free for BOTH phase-1 write and phase-3 read).
// LDS instr/thread: 96 -> 24. Predict headline 83.3 -> 80.5-82.
// Rejected: paired rcp (den_a*den_b ~ e^160 -> inf), W1 LDS staging (LDS
// 40.6KB -> 3 blk/CU cliff).
//   Math (verified in-harness R4/R10, absmax 0.0):
//   out[b] = sum_chunks [ Sc*(sumW2+b2) + sum_h W2[h] * sum_quads N(F)/P(F) ]
//   E = exp2(kC*u_qh), F = exp2(kC*v_bh); N deg3 (y folded), P deg4 (p0=1).
// ---------------------------------------------------------------------------
__global__ __launch_bounds__(256, 4) void fused_kernel(
    const float* __restrict__ input,
    const float* __restrict__ eq,
    const float* __restrict__ qx,
    const float* __restrict__ W1,
    const float* __restrict__ b1,
    const float* __restrict__ W2,
    const float* __restrict__ b2,
    float* __restrict__ out)
{
    __shared__ float4 c4_s[QPC * 256];       // 32 KB: [quad][swizzled chunk]
    __shared__ float in_s[RPB * D_IN_];
    __shared__ float qx_s[QCHUNK * 2];
    __shared__ float y_s[QCHUNK];            // -2*sin(qx.eq)
    __shared__ float part[4][NB];
    __shared__ float Sc_s, w2sum_s;

    const int t    = threadIdx.x;
    const int rb   = blockIdx.x & (NRB - 1); // row-block [0,128)
    const int qc   = blockIdx.x >> 7;        // q-chunk   [0,16)
    const int h    = t & 127;
    const int bg   = t >> 7;
    const int lane = t & 63;
    const int w    = t >> 6;

    // per-thread swizzled chunk ids (same expression on write & read side)
    const int cwn = (2 * h)     ^ (((2 * h)     >> 3) & 7);  // {n0..n3}
    const int cwp = (2 * h + 1) ^ (((2 * h + 1) >> 3) & 7);  // {p1..p4}

    // ---- phase 0: stage input rows + qx chunk; y + Sc (wave 0); sum W2 ----
    in_s[t] = input[rb * (RPB * D_IN_) + t];
    if (t < QCHUNK * 2) qx_s[t] = qx[qc * (QCHUNK * 2) + t];
    if (w == 0) {
        float s = 0.0f;
        if (lane < QCHUNK) {
            const int q = qc * QCHUNK + lane;
            const float a  = fmaf(qx[2 * q + 1], eq[1], qx[2 * q] * eq[0]);
            const float yv = sinf(a);
            y_s[lane] = -2.0f * yv;
            s = yv;
        }
        #pragma unroll
        for (int off = 32; off >= 1; off >>= 1)
            s += __shfl_down(s, off, 64);
        if (lane == 0) Sc_s = s;
    }
    if (w == 1) {
        float s = W2[lane] + W2[64 + lane];
        #pragma unroll
        for (int off = 32; off >= 1; off >>= 1)
            s += __shfl_down(s, off, 64);
        if (lane == 0) w2sum_s = s;
    }
    const float w2 = W2[h];
    __syncthreads();

    // ---- phase 1: coef tile; thread (h,bg) builds quads bg*4+{0..3} ----
    {
        const float w1a = W1[h], w1b = W1[H_N + h], bh = b1[h];
        #pragma unroll
        for (int k = 0; k < 4; ++k) {
            const int qd = bg * 4 + k;
            float n0 = 0, n1 = 0, n2 = 0, n3 = 0;
            float p1 = 0, p2 = 0, p3 = 0, p4 = 0;
            #pragma unroll
            for (int i = 0; i < 4; ++i) {
                const int ql = qd * 4 + i;
                const float x0 = qx_s[2 * ql], x1 = qx_s[2 * ql + 1];
                const float u = fmaf(x1, w1b, fmaf(x0, w1a, bh));
                const float E = __builtin_amdgcn_exp2f(u * kC);
                const float y = y_s[ql];
                n3 = fmaf(E, n2, fmaf(y, p3, n3));
                n2 = fmaf(E, n1, fmaf(y, p2, n2));
                n1 = fmaf(E, n0, fmaf(y, p1, n1));
                n0 = n0 + y;
                p4 = fmaf(E, p3, p4);
                p3 = fmaf(E, p2, p3);
                p2 = fmaf(E, p1, p2);
                p1 = p1 + E;
            }
            float4* dst = c4_s + qd * 256;
            dst[cwn] = make_float4(n0, n1, n2, n3);
            dst[cwp] = make_float4(p1, p2, p3, p4);
        }
    }

    // ---- phase 2: F for my 8 rows (streams W1) ----
    float F[NB], acc[NB];
    {
        float s[NB];
        #pragma unroll
        for (int r = 0; r < NB; ++r) s[r] = 0.0f;
        const float4* in4 = (const float4*)in_s;
        #pragma unroll
        for (int k = 0; k < 4; ++k) {
            const float wa = W1[(2 + 4 * k + 0) * H_N + h];
            const float wb = W1[(2 + 4 * k + 1) * H_N + h];
            const float wc = W1[(2 + 4 * k + 2) * H_N + h];
            const float wd = W1[(2 + 4 * k + 3) * H_N + h];
            #pragma unroll
            for (int r = 0; r < NB; ++r) {
                const float4 a = in4[(bg * NB + r) * 4 + k];
                float sr = s[r];
                sr = fmaf(a.x, wa, sr);
                sr = fmaf(a.y, wb, sr);
                sr = fmaf(a.z, wc, sr);
                sr = fmaf(a.w, wd, sr);
                s[r] = sr;
            }
        }
        #pragma unroll
        for (int r = 0; r < NB; ++r) {
            F[r] = __builtin_amdgcn_exp2f(s[r] * kC);
            acc[r] = 0.0f;
        }
    }
    __syncthreads();

    // ---- phase 3: rational inner loop; 2 ds_read_b128 per quad ----
    #pragma unroll 2
    for (int qd = 0; qd < QPC; ++qd) {
        const float4 cn = c4_s[qd * 256 + cwn];   // n0,n1,n2,n3
        const float4 cp = c4_s[qd * 256 + cwp];   // p1,p2,p3,p4
        #pragma unroll
        for (int r = 0; r < NB; ++r) {
            const float Fr  = F[r];
            const float den = fmaf(fmaf(fmaf(fmaf(cp.w, Fr, cp.z), Fr, cp.y), Fr, cp.x), Fr, 1.0f);
            const float num = fmaf(fmaf(fmaf(cn.w, Fr, cn.z), Fr, cn.y), Fr, cn.x);
            acc[r] = fmaf(num, __builtin_amdgcn_rcpf(den), acc[r]);
        }
    }

    // ---- epilogue: x W2[h], reduce over h, add per-chunk constant ----
    #pragma unroll
    for (int r = 0; r < NB; ++r) {
        float p = acc[r] * w2;
        #pragma unroll
        for (int off = 32; off >= 1; off >>= 1)
            p += __shfl_down(p, off, 64);
        if (lane == 0) part[w][r] = p;
    }
    __syncthreads();

    if (t < 16) {
        const int r = t & 7, g = t >> 3;
        const float k0c = Sc_s * (w2sum_s + b2[0]);
        const float s = part[2 * g][r] + part[2 * g + 1][r] + k0c;
        atomicAdd(out + rb * RPB + g * NB + r, s);
    }
}

// ---------------------------------------------------------------------------
extern "C" void kernel_launch(void* const* d_in, const int* in_sizes, int n_in,
                              void* d_out, int out_size, void* d_ws, size_t ws_size,
                              hipStream_t stream)
{
    (void)in_sizes; (void)n_in; (void)d_ws; (void)ws_size;
    const float* input = (const float*)d_in[0];
    const float* eq    = (const float*)d_in[1];
    const float* qx    = (const float*)d_in[2];
    const float* W1    = (const float*)d_in[3];
    const float* b1    = (const float*)d_in[4];
    const float* W2    = (const float*)d_in[5];
    const float* b2    = (const float*)d_in[6];
    float* out = (float*)d_out;

    hipMemsetAsync(d_out, 0, (size_t)out_size * sizeof(float), stream);
    // Single dispatch: grid 2048 = 128 row-blocks x 16 q-chunks, 4 blk/CU.
    fused_kernel<<<dim3(NRB * NQC), dim3(256), 0, stream>>>(
        input, eq, qx, W1, b1, W2, b2, out);
}

// Round 13
// 80.685 us; speedup vs baseline: 1.2885x; 1.0273x over previous
//
#include <hip/hip_runtime.h>
#include <math.h>

// Problem constants
#define B_N   2048
#define D_IN_ 16
#define Q_N   512
#define H_N   128

#define QCHUNK 32                      // q's per chunk
#define NQC    (Q_N / QCHUNK)          // 16
#define QPC    (QCHUNK / 4)            // 8 quads per chunk
#define NB     8                       // rows per thread
#define RPB    16                      // rows per block
#define NRB    (B_N / RPB)             // 128

static constexpr float kC = 2.88539008177792681472f;  // 2 * log2(e)

// ws layout (floats)
#define F_OFF   0                              // F[row*128+h], 262144
#define C4_OFF  (B_N * H_N)                    // float4 c4[...], 131072 floats
#define SC_OFF  (C4_OFF + NQC * QPC * 2 * H_N * 4)   // Sc[qc], 16
#define W2S_OFF (SC_OFF + NQC)                 // w2sum, 1
#define WS_FLOATS (W2S_OFF + 1)

// ---------------------------------------------------------------------------
// R13: two-stage precompute via d_ws (FREE scratch: the 268MB poison fill is
// unconditional — R4 vs R10/R12 proved it costs ~39.5us whether ws is used
// or not). Redundancy audit of R12: phase 2 (F[row][h]) recomputed by all 16
// q-chunk blocks (16x); phase 1 (coef[qc][h]) recomputed by all 128
// row-blocks (128x) — ~40% of per-thread work duplicates two tiny tables
// (F=1MB, coef=512KB, both L2-resident). R12's LDS-b128 experiment was
// NEUTRAL (83.3->82.9) -> LDS pipe not critical; issue count is.
//   Stage 1 (grid 1040): blocks [0,1024) compute F = exp2(kC*input.W1col);
//   blocks [1024,1040) compute coef tables (same recurrence as R12 phase 1,
//   same fma order -> bit-identical), Sc[qc], w2sum.
//   Stage 2 (grid 2048): pure rational loop on precomputed tables. No LDS
//   except 128B reduce buffer; ONE barrier; ~45% fewer VALU ops than R12.
// Predict headline 82.9 -> 77-80. Flat => ~15us kernel is barrier/latency
// structure, not work. Worse => dispatch-overhead model wrong, revert.
//   Math (verified in-harness R4/R10/R12, absmax 0.0):
//   out[b] = sum_qc [ Sc*(w2sum+b2) + sum_h W2[h] * sum_qd N(F)/P(F) ]
// ---------------------------------------------------------------------------
__global__ __launch_bounds__(256, 4) void precompute_kernel(
    const float* __restrict__ input,
    const float* __restrict__ eq,
    const float* __restrict__ qx,
    const float* __restrict__ W1,
    const float* __restrict__ b1,
    const float* __restrict__ W2,
    float* __restrict__ ws)
{
    const int t = threadIdx.x;
    const int blk = blockIdx.x;

    if (blk < 1024) {
        // ---- F table: 2 rows per block, thread = (row, h) ----
        const int row = blk * 2 + (t >> 7);
        const int h   = t & 127;
        const float* inr = input + row * D_IN_;
        float s = 0.0f;
        #pragma unroll
        for (int d = 0; d < D_IN_; ++d)
            s = fmaf(inr[d], W1[(2 + d) * H_N + h], s);
        ws[F_OFF + row * H_N + h] = __builtin_amdgcn_exp2f(s * kC);
        return;
    }

    // ---- coef blocks: one per q-chunk ----
    const int qc   = blk - 1024;
    const int h    = t & 127;
    const int bg   = t >> 7;
    const int lane = t & 63;
    const int w    = t >> 6;

    __shared__ float y_s[QCHUNK];

    if (w == 0) {                      // y + Sc (lanes < 32)
        float s = 0.0f;
        if (lane < QCHUNK) {
            const int q = qc * QCHUNK + lane;
            const float a  = fmaf(qx[2 * q + 1], eq[1], qx[2 * q] * eq[0]);
            const float yv = sinf(a);
            y_s[lane] = -2.0f * yv;
            s = yv;
        }
        #pragma unroll
        for (int off = 32; off >= 1; off >>= 1)
            s += __shfl_down(s, off, 64);
        if (lane == 0) ws[SC_OFF + qc] = s;
    }
    if (w == 1 && qc == 0) {           // w2sum (once globally)
        float s = W2[lane] + W2[64 + lane];
        #pragma unroll
        for (int off = 32; off >= 1; off >>= 1)
            s += __shfl_down(s, off, 64);
        if (lane == 0) ws[W2S_OFF] = s;
    }
    __syncthreads();

    // thread (h,bg) builds quads bg*4+{0..3} — identical recurrence to R12
    const float w1a = W1[h], w1b = W1[H_N + h], bh = b1[h];
    float4* c4 = (float4*)(ws + C4_OFF);
    #pragma unroll
    for (int k = 0; k < 4; ++k) {
        const int qd = bg * 4 + k;
        float n0 = 0, n1 = 0, n2 = 0, n3 = 0;
        float p1 = 0, p2 = 0, p3 = 0, p4 = 0;
        #pragma unroll
        for (int i = 0; i < 4; ++i) {
            const int ql = qd * 4 + i;
            const float x0 = qx[qc * (QCHUNK * 2) + 2 * ql];
            const float x1 = qx[qc * (QCHUNK * 2) + 2 * ql + 1];
            const float u = fmaf(x1, w1b, fmaf(x0, w1a, bh));
            const float E = __builtin_amdgcn_exp2f(u * kC);
            const float y = y_s[ql];
            n3 = fmaf(E, n2, fmaf(y, p3, n3));
            n2 = fmaf(E, n1, fmaf(y, p2, n2));
            n1 = fmaf(E, n0, fmaf(y, p1, n1));
            n0 = n0 + y;
            p4 = fmaf(E, p3, p4);
            p3 = fmaf(E, p2, p3);
            p2 = fmaf(E, p1, p2);
            p1 = p1 + E;
        }
        const int base = (qc * QPC + qd) * 2;
        c4[(base + 0) * H_N + h] = make_float4(n0, n1, n2, n3);
        c4[(base + 1) * H_N + h] = make_float4(p1, p2, p3, p4);
    }
}

// ---------------------------------------------------------------------------
__global__ __launch_bounds__(256, 4) void main_kernel(
    const float* __restrict__ ws,
    const float* __restrict__ W2,
    const float* __restrict__ b2,
    float* __restrict__ out)
{
    __shared__ float part[4][NB];

    const int t    = threadIdx.x;
    const int rb   = blockIdx.x & (NRB - 1); // row-block [0,128)
    const int qc   = blockIdx.x >> 7;        // q-chunk   [0,16)
    const int h    = t & 127;
    const int bg   = t >> 7;
    const int lane = t & 63;
    const int w    = t >> 6;

    const float w2 = W2[h];

    // F for my 8 rows (coalesced: 64 lanes read consecutive h)
    float F[NB], acc[NB];
    #pragma unroll
    for (int r = 0; r < NB; ++r) {
        const int row = rb * RPB + bg * NB + r;
        F[r]   = ws[F_OFF + row * H_N + h];
        acc[r] = 0.0f;
    }

    // rational loop over this chunk's 8 quads; coefs from L2-resident table
    const float4* c4 = (const float4*)(ws + C4_OFF);
    #pragma unroll 2
    for (int qd = 0; qd < QPC; ++qd) {
        const int base = (qc * QPC + qd) * 2;
        const float4 cn = c4[(base + 0) * H_N + h];   // n0,n1,n2,n3
        const float4 cp = c4[(base + 1) * H_N + h];   // p1,p2,p3,p4
        #pragma unroll
        for (int r = 0; r < NB; ++r) {
            const float Fr  = F[r];
            const float den = fmaf(fmaf(fmaf(fmaf(cp.w, Fr, cp.z), Fr, cp.y), Fr, cp.x), Fr, 1.0f);
            const float num = fmaf(fmaf(fmaf(cn.w, Fr, cn.z), Fr, cn.y), Fr, cn.x);
            acc[r] = fmaf(num, __builtin_amdgcn_rcpf(den), acc[r]);
        }
    }

    // epilogue: x W2[h], reduce over h, add per-chunk constant
    #pragma unroll
    for (int r = 0; r < NB; ++r) {
        float p = acc[r] * w2;
        #pragma unroll
        for (int off = 32; off >= 1; off >>= 1)
            p += __shfl_down(p, off, 64);
        if (lane == 0) part[w][r] = p;
    }
    __syncthreads();

    if (t < 16) {
        const int r = t & 7, g = t >> 3;
        const float k0c = ws[SC_OFF + qc] * (ws[W2S_OFF] + b2[0]);
        const float s = part[2 * g][r] + part[2 * g + 1][r] + k0c;
        atomicAdd(out + rb * RPB + g * NB + r, s);
    }
}

// ---------------------------------------------------------------------------
// Fallback (= R12 kernel) if ws is ever too small. Kept for safety.
// ---------------------------------------------------------------------------
__global__ __launch_bounds__(256, 4) void fused_fallback(
    const float* __restrict__ input,
    const float* __restrict__ eq,
    const float* __restrict__ qx,
    const float* __restrict__ W1,
    const float* __restrict__ b1,
    const float* __restrict__ W2,
    const float* __restrict__ b2,
    float* __restrict__ out)
{
    __shared__ float4 c4_s[QPC * 256];
    __shared__ float in_s[RPB * D_IN_];
    __shared__ float qx_s[QCHUNK * 2];
    __shared__ float y_s[QCHUNK];
    __shared__ float part[4][NB];
    __shared__ float Sc_s, w2sum_s;

    const int t    = threadIdx.x;
    const int rb   = blockIdx.x & (NRB - 1);
    const int qc   = blockIdx.x >> 7;
    const int h    = t & 127;
    const int bg   = t >> 7;
    const int lane = t & 63;
    const int w    = t >> 6;
    const int cwn = (2 * h)     ^ (((2 * h)     >> 3) & 7);
    const int cwp = (2 * h + 1) ^ (((2 * h + 1) >> 3) & 7);

    in_s[t] = input[rb * (RPB * D_IN_) + t];
    if (t < QCHUNK * 2) qx_s[t] = qx[qc * (QCHUNK * 2) + t];
    if (w == 0) {
        float s = 0.0f;
        if (lane < QCHUNK) {
            const int q = qc * QCHUNK + lane;
            const float a  = fmaf(qx[2 * q + 1], eq[1], qx[2 * q] * eq[0]);
            const float yv = sinf(a);
            y_s[lane] = -2.0f * yv;
            s = yv;
        }
        #pragma unroll
        for (int off = 32; off >= 1; off >>= 1)
            s += __shfl_down(s, off, 64);
        if (lane == 0) Sc_s = s;
    }
    if (w == 1) {
        float s = W2[lane] + W2[64 + lane];
        #pragma unroll
        for (int off = 32; off >= 1; off >>= 1)
            s += __shfl_down(s, off, 64);
        if (lane == 0) w2sum_s = s;
    }
    const float w2 = W2[h];
    __syncthreads();

    {
        const float w1a = W1[h], w1b = W1[H_N + h], bh = b1[h];
        #pragma unroll
        for (int k = 0; k < 4; ++k) {
            const int qd = bg * 4 + k;
            float n0 = 0, n1 = 0, n2 = 0, n3 = 0;
            float p1 = 0, p2 = 0, p3 = 0, p4 = 0;
            #pragma unroll
            for (int i = 0; i < 4; ++i) {
                const int ql = qd * 4 + i;
                const float x0 = qx_s[2 * ql], x1 = qx_s[2 * ql + 1];
                const float u = fmaf(x1, w1b, fmaf(x0, w1a, bh));
                const float E = __builtin_amdgcn_exp2f(u * kC);
                const float y = y_s[ql];
                n3 = fmaf(E, n2, fmaf(y, p3, n3));
                n2 = fmaf(E, n1, fmaf(y, p2, n2));
                n1 = fmaf(E, n0, fmaf(y, p1, n1));
                n0 = n0 + y;
                p4 = fmaf(E, p3, p4);
                p3 = fmaf(E, p2, p3);
                p2 = fmaf(E, p1, p2);
                p1 = p1 + E;
            }
            float4* dst = c4_s + qd * 256;
            dst[cwn] = make_float4(n0, n1, n2, n3);
            dst[cwp] = make_float4(p1, p2, p3, p4);
        }
    }

    float F[NB], acc[NB];
    {
        float s[NB];
        #pragma unroll
        for (int r = 0; r < NB; ++r) s[r] = 0.0f;
        const float4* in4 = (const float4*)in_s;
        #pragma unroll
        for (int k = 0; k < 4; ++k) {
            const float wa = W1[(2 + 4 * k + 0) * H_N + h];
            const float wb = W1[(2 + 4 * k + 1) * H_N + h];
            const float wc = W1[(2 + 4 * k + 2) * H_N + h];
            const float wd = W1[(2 + 4 * k + 3) * H_N + h];
            #pragma unroll
            for (int r = 0; r < NB; ++r) {
                const float4 a = in4[(bg * NB + r) * 4 + k];
                float sr = s[r];
                sr = fmaf(a.x, wa, sr);
                sr = fmaf(a.y, wb, sr);
                sr = fmaf(a.z, wc, sr);
                sr = fmaf(a.w, wd, sr);
                s[r] = sr;
            }
        }
        #pragma unroll
        for (int r = 0; r < NB; ++r) {
            F[r] = __builtin_amdgcn_exp2f(s[r] * kC);
            acc[r] = 0.0f;
        }
    }
    __syncthreads();

    #pragma unroll 2
    for (int qd = 0; qd < QPC; ++qd) {
        const float4 cn = c4_s[qd * 256 + cwn];
        const float4 cp = c4_s[qd * 256 + cwp];
        #pragma unroll
        for (int r = 0; r < NB; ++r) {
            const float Fr  = F[r];
            const float den = fmaf(fmaf(fmaf(fmaf(cp.w, Fr, cp.z), Fr, cp.y), Fr, cp.x), Fr, 1.0f);
            const float num = fmaf(fmaf(fmaf(cn.w, Fr, cn.z), Fr, cn.y), Fr, cn.x);
            acc[r] = fmaf(num, __builtin_amdgcn_rcpf(den), acc[r]);
        }
    }

    #pragma unroll
    for (int r = 0; r < NB; ++r) {
        float p = acc[r] * w2;
        #pragma unroll
        for (int off = 32; off >= 1; off >>= 1)
            p += __shfl_down(p, off, 64);
        if (lane == 0) part[w][r] = p;
    }
    __syncthreads();

    if (t < 16) {
        const int r = t & 7, g = t >> 3;
        const float k0c = Sc_s * (w2sum_s + b2[0]);
        const float s = part[2 * g][r] + part[2 * g + 1][r] + k0c;
        atomicAdd(out + rb * RPB + g * NB + r, s);
    }
}

// ---------------------------------------------------------------------------
extern "C" void kernel_launch(void* const* d_in, const int* in_sizes, int n_in,
                              void* d_out, int out_size, void* d_ws, size_t ws_size,
                              hipStream_t stream)
{
    (void)in_sizes; (void)n_in;
    const float* input = (const float*)d_in[0];
    const float* eq    = (const float*)d_in[1];
    const float* qx    = (const float*)d_in[2];
    const float* W1    = (const float*)d_in[3];
    const float* b1    = (const float*)d_in[4];
    const float* W2    = (const float*)d_in[5];
    const float* b2    = (const float*)d_in[6];
    float* out = (float*)d_out;

    hipMemsetAsync(d_out, 0, (size_t)out_size * sizeof(float), stream);

    if (d_ws != nullptr && ws_size >= (size_t)WS_FLOATS * sizeof(float)) {
        float* ws = (float*)d_ws;
        precompute_kernel<<<dim3(1024 + NQC), dim3(256), 0, stream>>>(
            input, eq, qx, W1, b1, W2, ws);
        main_kernel<<<dim3(NRB * NQC), dim3(256), 0, stream>>>(
            ws, W2, b2, out);
    } else {
        fused_fallback<<<dim3(NRB * NQC), dim3(256), 0, stream>>>(
            input, eq, qx, W1, b1, W2, b2, out);
    }
}